// Round 1
// 62.957 us; speedup vs baseline: 1.0147x; 1.0147x over previous
//
#include <hip/hip_runtime.h>
#include <math.h>

// Hawkes univariate NLL, multi-block version.
//
// Identity (x sorted ascending):
//   excite[j]/(alpha*w) = S_j = exp(-w*x_j) * sum_{i<j} exp(w*x_i)
// -> O(N) prefix scan instead of the O(N^2) pairwise matrix.
//
// Parallel decomposition: each row is split into CHUNKS chunks, one block per
// chunk. A block obtains its cross-chunk exclusive prefix base
//   E_c = sum_{i < c*M} exp(w*x_i)
// by redundantly re-reading the row prefix (worst case 32 KB, L2/L3-resident
// since all blocks read the same data) — no grid sync, no cooperative launch.
// Per-element transcendentals reduced:
//   exp(-w*x_j)            == 1/ys_j           (v_rcp_f32 instead of v_exp_f32)
//   alpha*(1-e^{-w(1-x)})  == alpha - (alpha*e^{-w}) * ys_j
// Ties (delta==0, masked by the reference) are counted as exp(0)=1; with
// ~24-bit uniforms over 8192 samples that's a handful of pairs, each
// perturbing one log term by <= 1 -> error << threshold (~2263).
//
// Cross-block combine: hipMemsetAsync(out, 0) then one device-scope
// atomicAdd per block (device-scope by default on gfx950; stream order
// guarantees the memset precedes the kernel, graph-capture-safe).

#define BLOCK   256
#define CHUNKS  16                  // chunks per row
#define NROW    8192
#define M       (NROW / CHUNKS)     // 512 elements per chunk
#define ITEMS   (M / BLOCK)         // 2 per thread
#define NWAVES  (BLOCK / 64)        // 4

__launch_bounds__(BLOCK)
__global__ void hawkes_nll_kernel(const float* __restrict__ x,
                                  const float* __restrict__ mu_p,
                                  const float* __restrict__ alpha_p,
                                  const float* __restrict__ w_p,
                                  float* __restrict__ out) {
    const float mu    = mu_p[0];
    const float alpha = alpha_p[0];
    const float w     = w_p[0];
    const float aw    = alpha * w;
    const float cneg  = alpha * __expf(-w);   // alpha*e^{-w}

    const int tid  = threadIdx.x;
    const int lane = tid & 63;
    const int wave = tid >> 6;

    const int b = blockIdx.x / CHUNKS;        // batch row
    const int c = blockIdx.x % CHUNKS;        // chunk within row

    const float* xb = x + (size_t)b * NROW;

    __shared__ float  s_pre[NWAVES];          // phase-1 wave partials
    __shared__ float  s_scan[NWAVES];         // wave scan totals
    __shared__ double s_pos[NWAVES];
    __shared__ double s_neg[NWAVES];

    // ---- Phase 1: E = sum_{i < c*M} exp(w*x_i) (redundant recompute) ----
    float esum = 0.0f;
    {
        const float4* x4 = (const float4*)xb;
        const int npre4 = (c * M) >> 2;       // float4s before our chunk
        for (int i = tid; i < npre4; i += BLOCK) {
            float4 v = x4[i];
            esum += __expf(w * v.x) + __expf(w * v.y)
                  + __expf(w * v.z) + __expf(w * v.w);
        }
#pragma unroll
        for (int off = 32; off > 0; off >>= 1)
            esum += __shfl_down(esum, off, 64);
        if (lane == 0) s_pre[wave] = esum;
    }

    // ---- Phase 2: local chunk load + per-thread sums ----
    const int base = c * M + tid * ITEMS;
    float xs[ITEMS], ys[ITEMS];
    float tsum = 0.0f;
#pragma unroll
    for (int i = 0; i < ITEMS; ++i) {
        xs[i] = xb[base + i];
        ys[i] = __expf(w * xs[i]);
        tsum += ys[i];
    }

    // wave-level inclusive scan (64 lanes)
    float v = tsum;
#pragma unroll
    for (int off = 1; off < 64; off <<= 1) {
        float n = __shfl_up(v, off, 64);
        if (lane >= off) v += n;
    }
    if (lane == 63) s_scan[wave] = v;
    __syncthreads();

    float E = 0.0f;
#pragma unroll
    for (int i = 0; i < NWAVES; ++i) E += s_pre[i];
    float wavepre = 0.0f;
#pragma unroll
    for (int i = 0; i < NWAVES; ++i) if (i < wave) wavepre += s_scan[i];

    // exclusive prefix for this thread's first element
    float run = E + wavepre + (v - tsum);

    // ---- Phase 3: per-element pos/neg terms ----
    double pos_sum = 0.0, neg_sum = 0.0;
#pragma unroll
    for (int i = 0; i < ITEMS; ++i) {
        // exp(-w*x) == 1/ys  -> v_rcp_f32, no second exp
        float S = run * __builtin_amdgcn_rcpf(ys[i]);
        pos_sum += (double)__logf(mu + aw * S);
        neg_sum += (double)(alpha - cneg * ys[i]);
        run += ys[i];
    }

    // ---- Phase 4: block reduction + device-scope combine ----
#pragma unroll
    for (int off = 32; off > 0; off >>= 1) {
        pos_sum += __shfl_down(pos_sum, off, 64);
        neg_sum += __shfl_down(neg_sum, off, 64);
    }
    if (lane == 0) { s_pos[wave] = pos_sum; s_neg[wave] = neg_sum; }
    __syncthreads();
    if (tid == 0) {
        double P = 0.0, Ng = 0.0;
#pragma unroll
        for (int i = 0; i < NWAVES; ++i) { P += s_pos[i]; Ng += s_neg[i]; }
        float partial = (float)(Ng - P);
        if (blockIdx.x == 0) {
            const double T_HORIZON = 1.0;
            const double REG = 0.01;
            partial += (float)((double)mu * T_HORIZON
                     + REG * (-log((double)mu) - log((double)alpha)
                              - log((double)w)));
        }
        atomicAdd(out, partial);
    }
}

extern "C" void kernel_launch(void* const* d_in, const int* in_sizes, int n_in,
                              void* d_out, int out_size, void* d_ws, size_t ws_size,
                              hipStream_t stream) {
    const float* x     = (const float*)d_in[0];
    const float* mu    = (const float*)d_in[1];
    const float* alpha = (const float*)d_in[2];
    const float* w     = (const float*)d_in[3];
    float* out = (float*)d_out;

    const int B = in_sizes[0] / NROW;   // element-count convention: 16384/8192 = 2

    hipMemsetAsync(out, 0, sizeof(float), stream);
    hipLaunchKernelGGL(hawkes_nll_kernel, dim3(B * CHUNKS), dim3(BLOCK), 0, stream,
                       x, mu, alpha, w, out);
}